// Round 1
// 790.620 us; speedup vs baseline: 1.0922x; 1.0922x over previous
//
#include <hip/hip_runtime.h>
#include <hip/hip_bf16.h>

#define Mdim 4096
#define Kdim 4096
#define Ndim 12288

typedef __attribute__((ext_vector_type(8))) short short8;
typedef __attribute__((ext_vector_type(4))) float floatx4;
typedef __attribute__((ext_vector_type(4))) int intx4;
typedef __attribute__((ext_vector_type(4))) unsigned short ushortx4;
typedef __attribute__((ext_vector_type(8))) unsigned short ushortx8;

static __device__ __forceinline__ unsigned short f2bf(float x) {
    __hip_bfloat16 h = __float2bfloat16(x);
    return __builtin_bit_cast(unsigned short, h);
}

// async 16B global -> LDS (LDS dst = wave-uniform base + lane*16)
static __device__ __forceinline__ void gload_lds16(const unsigned short* g, unsigned short* l) {
    __builtin_amdgcn_global_load_lds(
        (const __attribute__((address_space(1))) unsigned int*)g,
        (__attribute__((address_space(3))) unsigned int*)l,
        16, 0, 0);
}

// ---------------- Pre-pass 1: Q[k][n] int32 codes -> Wt[n][k] bf16 -----------
__global__ void __launch_bounds__(256)
dequant_transpose(const int* __restrict__ Q, const float* __restrict__ S,
                  const float* __restrict__ Z, unsigned short* __restrict__ Wt)
{
    __shared__ unsigned short Ls[64][72];
    const int t     = threadIdx.x;
    const int kbase = blockIdx.x * 256;
    const int n0    = blockIdx.y * 64;
    const int tn = t & 15, tk = t >> 4;
    const int nc = tn * 4;
    const int n_out  = t >> 2;
    const int kc_out = (t & 3) * 16;

    #pragma unroll
    for (int s = 0; s < 4; ++s) {
        const int k0 = kbase + s * 64;
        const int g  = k0 >> 6;
        const floatx4 s4 = *reinterpret_cast<const floatx4*>(&S[(size_t)g * Ndim + n0 + nc]);
        const floatx4 z4 = *reinterpret_cast<const floatx4*>(&Z[(size_t)g * Ndim + n0 + nc]);
        intx4 q[4];
        #pragma unroll
        for (int r = 0; r < 4; ++r)
            q[r] = *reinterpret_cast<const intx4*>(&Q[(size_t)(k0 + tk * 4 + r) * Ndim + n0 + nc]);
        if (s) __syncthreads();
        #pragma unroll
        for (int j = 0; j < 4; ++j) {
            const float sv = s4[j], zv = z4[j];
            ushortx4 w;
            w.x = f2bf(fmaf((float)q[0][j], sv, zv));
            w.y = f2bf(fmaf((float)q[1][j], sv, zv));
            w.z = f2bf(fmaf((float)q[2][j], sv, zv));
            w.w = f2bf(fmaf((float)q[3][j], sv, zv));
            *reinterpret_cast<ushortx4*>(&Ls[nc + j][tk * 4]) = w;
        }
        __syncthreads();
        const ushortx8 a = *reinterpret_cast<const ushortx8*>(&Ls[n_out][kc_out]);
        const ushortx8 b = *reinterpret_cast<const ushortx8*>(&Ls[n_out][kc_out + 8]);
        unsigned short* dst = &Wt[(size_t)(n0 + n_out) * Kdim + k0 + kc_out];
        *reinterpret_cast<ushortx8*>(dst)     = a;
        *reinterpret_cast<ushortx8*>(dst + 8) = b;
    }
}

// ---------------- Pre-pass 2: X fp32 -> bf16 ---------------------------------
__global__ void __launch_bounds__(256)
xconv(const float* __restrict__ X, unsigned short* __restrict__ Xw)
{
    const size_t i = ((size_t)blockIdx.x * 256 + threadIdx.x) * 8;
    const floatx4 a = *reinterpret_cast<const floatx4*>(&X[i]);
    const floatx4 b = *reinterpret_cast<const floatx4*>(&X[i + 4]);
    ushortx8 w;
    w[0] = f2bf(a.x); w[1] = f2bf(a.y); w[2] = f2bf(a.z); w[3] = f2bf(a.w);
    w[4] = f2bf(b.x); w[5] = f2bf(b.y); w[6] = f2bf(b.z); w[7] = f2bf(b.w);
    *reinterpret_cast<ushortx8*>(&Xw[i]) = w;
}

// ---------------- Main GEMM: 256x256x64, 8-wave, 8-phase counted-vmcnt -------
// LDS rows = 64 shorts (128 B); 16B chunk c of row r stored at chunk c^(r&7).
// Per K-tile (BK=64), 4 phases: P1 (M0xN01), P2 (M1xN01), P3 (M0xN23), P4 (M1xN23).
// A-frags fully held in regs after P2 -> A region restaged at P3/P4 (tile u+2).
// B of tile u+1 staged at P1/P2 into the other buffer.
// vmcnt(4) once per tile at P4 (tail: vmcnt(0)) -> 2 half-tile stages stay in flight.

#define STAGE_A(c, kt, h) do { \
    const unsigned short* sp_ = A + aoff + (size_t)((h) * 128) * Kdim + (size_t)(kt) * 64; \
    unsigned short* dp_ = &As[c][((h) * 128 + wave * 16) * 64]; \
    gload_lds16(sp_, dp_); \
    gload_lds16(sp_ + (size_t)8 * Kdim, dp_ + 8 * 64); \
} while (0)

#define STAGE_B(c, kt, h) do { \
    const unsigned short* sp_ = B + boff + (size_t)((h) * 128) * Kdim + (size_t)(kt) * 64; \
    unsigned short* dp_ = &Bs[c][((h) * 128 + wave * 16) * 64]; \
    gload_lds16(sp_, dp_); \
    gload_lds16(sp_ + (size_t)8 * Kdim, dp_ + 8 * 64); \
} while (0)

#define LDA_(c, i, kh) (*reinterpret_cast<const short8*>( \
    &As[c][(wm + (i) * 16 + lrow) * 64 + (((kh) * 4 + quad) ^ lsw) * 8]))
#define LDB_(c, j, kh) (*reinterpret_cast<const short8*>( \
    &Bs[c][(wn + (j) * 16 + lrow) * 64 + (((kh) * 4 + quad) ^ lsw) * 8]))

#define PHASE_SYNC() do { \
    __builtin_amdgcn_s_barrier(); \
    asm volatile("s_waitcnt lgkmcnt(0)" ::: "memory"); \
    __builtin_amdgcn_sched_barrier(0); \
} while (0)

#define MFMA_QUAD(ILO, JO) do { \
    __builtin_amdgcn_s_setprio(1); \
    _Pragma("unroll") \
    for (int i_ = 0; i_ < 4; ++i_) { \
        _Pragma("unroll") \
        for (int jj_ = 0; jj_ < 2; ++jj_) { \
            acc[(ILO) + i_][(JO) + jj_] = __builtin_amdgcn_mfma_f32_16x16x32_bf16( \
                af[(ILO) + i_][0], bfr[jj_][0], acc[(ILO) + i_][(JO) + jj_], 0, 0, 0); \
            acc[(ILO) + i_][(JO) + jj_] = __builtin_amdgcn_mfma_f32_16x16x32_bf16( \
                af[(ILO) + i_][1], bfr[jj_][1], acc[(ILO) + i_][(JO) + jj_], 0, 0, 0); \
        } \
    } \
    __builtin_amdgcn_s_setprio(0); \
} while (0)

__global__ void __launch_bounds__(512, 2)
gemm_bf16_8p(const unsigned short* __restrict__ A, const unsigned short* __restrict__ B,
             const float* __restrict__ bias, float* __restrict__ O)
{
    __shared__ unsigned short As[2][256 * 64];   // 64 KiB
    __shared__ unsigned short Bs[2][256 * 64];   // 64 KiB

    constexpr int NT = Kdim / 64;                // 64 K-tiles

    // XCD-aware bijective swizzle (768 % 8 == 0), then 8-row-band grouping
    const int nblk = Ndim / 256;                 // 48
    const int cpx  = (Mdim / 256) * nblk / 8;    // 96 blocks per XCD
    const int bid  = blockIdx.x;
    const int swz  = (bid & 7) * cpx + (bid >> 3);
    const int gsz  = 8 * nblk;                   // 384
    const int grp  = swz / gsz;
    const int r    = swz % gsz;
    const int m0   = (grp * 8 + (r & 7)) * 256;
    const int n0   = (r >> 3) * 256;

    const int t    = threadIdx.x;
    const int wave = t >> 6;                     // 0..7
    const int lane = t & 63;
    const int wm   = (wave >> 2) * 128;          // wave rows: 128-high half
    const int wn   = (wave & 3) * 64;            // wave cols: 64-wide quarter
    const int lrow = lane & 15;
    const int quad = lane >> 4;
    const int lsw  = lrow & 7;

    // staging: lane fills physical chunk (lane&7) of row (lane>>3) in an 8-row slab;
    // that chunk must hold logical k-chunk (lane&7)^(row&7)
    const int srow = lane >> 3;
    const int scol = ((lane & 7) ^ srow) * 8;
    const size_t aoff = (size_t)(m0 + wave * 16 + srow) * Kdim + scol;
    const size_t boff = (size_t)(n0 + wave * 16 + srow) * Kdim + scol;

    floatx4 acc[8][4];
    #pragma unroll
    for (int i = 0; i < 8; ++i)
        #pragma unroll
        for (int j = 0; j < 4; ++j)
            acc[i][j] = floatx4{0.f, 0.f, 0.f, 0.f};

    short8 af[8][2];
    short8 bfr[2][2];

    // prologue: tile0 (A+B) -> buf0, tile1 A -> buf1 (B of tile1 staged in tile0.P1/P2)
    STAGE_A(0, 0, 0); STAGE_A(0, 0, 1);
    STAGE_B(0, 0, 0); STAGE_B(0, 0, 1);
    STAGE_A(1, 1, 0); STAGE_A(1, 1, 1);
    asm volatile("s_waitcnt vmcnt(4)" ::: "memory");
    __builtin_amdgcn_s_barrier();
    __builtin_amdgcn_sched_barrier(0);

    for (int u = 0; u < NT; ++u) {
        const int c = u & 1;

        // ---- P1: ds A-M0 (8) + B-N01 (4); stage B(u+1) h0; MFMA M0 x N01
        #pragma unroll
        for (int i = 0; i < 4; ++i) { af[i][0] = LDA_(c, i, 0); af[i][1] = LDA_(c, i, 1); }
        #pragma unroll
        for (int j = 0; j < 2; ++j) { bfr[j][0] = LDB_(c, j, 0); bfr[j][1] = LDB_(c, j, 1); }
        if (u + 1 < NT) STAGE_B(c ^ 1, u + 1, 0);
        PHASE_SYNC();
        MFMA_QUAD(0, 0);
        __builtin_amdgcn_s_barrier();

        // ---- P2: ds A-M1 (8); stage B(u+1) h1; MFMA M1 x N01
        #pragma unroll
        for (int i = 4; i < 8; ++i) { af[i][0] = LDA_(c, i, 0); af[i][1] = LDA_(c, i, 1); }
        if (u + 1 < NT) STAGE_B(c ^ 1, u + 1, 1);
        PHASE_SYNC();
        MFMA_QUAD(4, 0);
        __builtin_amdgcn_s_barrier();

        // ---- P3: ds B-N23 (4); stage A(u+2) h0 (A region of buf c free after P2);
        //          MFMA M0 x N23
        #pragma unroll
        for (int j = 0; j < 2; ++j) { bfr[j][0] = LDB_(c, j + 2, 0); bfr[j][1] = LDB_(c, j + 2, 1); }
        if (u + 2 < NT) STAGE_A(c, u + 2, 0);
        PHASE_SYNC();
        MFMA_QUAD(0, 2);
        __builtin_amdgcn_s_barrier();

        // ---- P4: stage A(u+2) h1; MFMA M1 x N23 (regs only); counted vmcnt; barrier
        if (u + 2 < NT) STAGE_A(c, u + 2, 1);
        MFMA_QUAD(4, 2);
        if (u < NT - 2) { asm volatile("s_waitcnt vmcnt(4)" ::: "memory"); }
        else            { asm volatile("s_waitcnt vmcnt(0)" ::: "memory"); }
        __builtin_amdgcn_s_barrier();
        __builtin_amdgcn_sched_barrier(0);
    }

    // epilogue
    #pragma unroll
    for (int j = 0; j < 4; ++j) {
        const int col = n0 + wn + j * 16 + lrow;
        const float bv = bias[col];
        #pragma unroll
        for (int i = 0; i < 8; ++i) {
            const int rbase = m0 + wm + i * 16 + quad * 4;
            #pragma unroll
            for (int rr = 0; rr < 4; ++rr)
                O[(size_t)(rbase + rr) * Ndim + col] = acc[i][j][rr] + bv;
        }
    }
}

// ---------------- Fallback (fused, ws-independent) ---------------------------
__global__ void __launch_bounds__(256)
w2a16_gemm_fb(const float* __restrict__ X, const int* __restrict__ Q,
              const float* __restrict__ S, const float* __restrict__ Z,
              const float* __restrict__ bias, float* __restrict__ O)
{
    __shared__ unsigned short Asf[128][72];
    __shared__ unsigned short Bsf[128][72];
    const int t  = threadIdx.x;
    const int n0 = blockIdx.x * 128;
    const int m0 = blockIdx.y * 128;
    const int wave = t >> 6, lane = t & 63;
    const int wm = (wave & 1) * 64, wn = (wave >> 1) * 64;
    const int lrow = lane & 15, quad = lane >> 4;
    floatx4 acc[4][4];
    #pragma unroll
    for (int i = 0; i < 4; ++i)
        #pragma unroll
        for (int j = 0; j < 4; ++j) acc[i][j] = floatx4{0.f, 0.f, 0.f, 0.f};
    const int a_row0 = t >> 4, a_c = (t & 15) * 4;
    const int b_n = t & 127, b_k0 = (t >> 7) * 32;
    for (int k0 = 0; k0 < Kdim; k0 += 64) {
        #pragma unroll
        for (int i = 0; i < 8; ++i) {
            const int row = a_row0 + i * 16;
            const floatx4 v = *reinterpret_cast<const floatx4*>(
                &X[(size_t)(m0 + row) * Kdim + k0 + a_c]);
            ushortx4 w;
            w.x = f2bf(v.x); w.y = f2bf(v.y); w.z = f2bf(v.z); w.w = f2bf(v.w);
            *reinterpret_cast<ushortx4*>(&Asf[row][a_c]) = w;
        }
        const int g = k0 >> 6;
        const float s = S[(size_t)g * Ndim + n0 + b_n];
        const float z = Z[(size_t)g * Ndim + n0 + b_n];
        #pragma unroll
        for (int i = 0; i < 8; ++i) {
            const int kk = b_k0 + i * 4;
            const int* qp = &Q[(size_t)(k0 + kk) * Ndim + n0 + b_n];
            ushortx4 w;
            w.x = f2bf(fmaf((float)qp[0],                s, z));
            w.y = f2bf(fmaf((float)qp[(size_t)Ndim],     s, z));
            w.z = f2bf(fmaf((float)qp[(size_t)2 * Ndim], s, z));
            w.w = f2bf(fmaf((float)qp[(size_t)3 * Ndim], s, z));
            *reinterpret_cast<ushortx4*>(&Bsf[b_n][kk]) = w;
        }
        __syncthreads();
        #pragma unroll
        for (int kk = 0; kk < 64; kk += 32) {
            short8 afv[4], bfv[4];
            #pragma unroll
            for (int i = 0; i < 4; ++i)
                afv[i] = *reinterpret_cast<const short8*>(&Asf[wm + i * 16 + lrow][kk + quad * 8]);
            #pragma unroll
            for (int j = 0; j < 4; ++j)
                bfv[j] = *reinterpret_cast<const short8*>(&Bsf[wn + j * 16 + lrow][kk + quad * 8]);
            #pragma unroll
            for (int i = 0; i < 4; ++i)
                #pragma unroll
                for (int j = 0; j < 4; ++j)
                    acc[i][j] = __builtin_amdgcn_mfma_f32_16x16x32_bf16(afv[i], bfv[j], acc[i][j], 0, 0, 0);
        }
        __syncthreads();
    }
    #pragma unroll
    for (int j = 0; j < 4; ++j) {
        const int col = n0 + wn + j * 16 + lrow;
        const float bv = bias[col];
        #pragma unroll
        for (int i = 0; i < 4; ++i) {
            const int rbase = m0 + wm + i * 16 + quad * 4;
            #pragma unroll
            for (int rr = 0; rr < 4; ++rr)
                O[(size_t)(rbase + rr) * Ndim + col] = acc[i][j][rr] + bv;
        }
    }
}

extern "C" void kernel_launch(void* const* d_in, const int* in_sizes, int n_in,
                              void* d_out, int out_size, void* d_ws, size_t ws_size,
                              hipStream_t stream) {
    const float* X  = (const float*)d_in[0];
    const int*   Q  = (const int*)d_in[1];
    const float* S  = (const float*)d_in[2];
    const float* Z  = (const float*)d_in[3];
    const float* Bi = (const float*)d_in[4];
    float* O = (float*)d_out;

    const size_t wt_bytes = (size_t)Kdim * Ndim * 2;
    const size_t xw_bytes = (size_t)Mdim * Kdim * 2;

    if (ws_size >= wt_bytes + xw_bytes) {
        unsigned short* Wt = (unsigned short*)d_ws;
        unsigned short* Xw = (unsigned short*)((char*)d_ws + wt_bytes);

        dim3 g1(Kdim / 256, Ndim / 64);                   // (16, 192)
        hipLaunchKernelGGL(dequant_transpose, g1, dim3(256), 0, stream, Q, S, Z, Wt);

        const int xblocks = (Mdim * Kdim) / (256 * 8);    // 8192
        hipLaunchKernelGGL(xconv, dim3(xblocks), dim3(256), 0, stream, X, Xw);

        const int nblocks = (Mdim / 256) * (Ndim / 256);  // 768
        hipLaunchKernelGGL(gemm_bf16_8p, dim3(nblocks), dim3(512), 0, stream, Xw, Wt, Bi, O);
    } else {
        dim3 grid(Ndim / 128, Mdim / 128);
        hipLaunchKernelGGL(w2a16_gemm_fb, grid, dim3(256), 0, stream, X, Q, S, Z, Bi, O);
    }
}

// Round 2
// 768.823 us; speedup vs baseline: 1.1232x; 1.0284x over previous
//
#include <hip/hip_runtime.h>
#include <hip/hip_bf16.h>

#define Mdim 4096
#define Kdim 4096
#define Ndim 12288

typedef __attribute__((ext_vector_type(8))) short short8;
typedef __attribute__((ext_vector_type(4))) float floatx4;
typedef __attribute__((ext_vector_type(4))) int intx4;
typedef __attribute__((ext_vector_type(4))) unsigned short ushortx4;
typedef __attribute__((ext_vector_type(8))) unsigned short ushortx8;

static __device__ __forceinline__ unsigned short f2bf(float x) {
    __hip_bfloat16 h = __float2bfloat16(x);
    return __builtin_bit_cast(unsigned short, h);
}

// async 16B global -> LDS (LDS dst = wave-uniform base + lane*16)
static __device__ __forceinline__ void gload_lds16(const unsigned short* g, unsigned short* l) {
    __builtin_amdgcn_global_load_lds(
        (const __attribute__((address_space(1))) unsigned int*)g,
        (__attribute__((address_space(3))) unsigned int*)l,
        16, 0, 0);
}

// ---------------- Pre-pass 1: Q[k][n] int32 codes -> Wt[n][k] bf16 -----------
__global__ void __launch_bounds__(256)
dequant_transpose(const int* __restrict__ Q, const float* __restrict__ S,
                  const float* __restrict__ Z, unsigned short* __restrict__ Wt)
{
    __shared__ unsigned short Ls[64][72];
    const int t     = threadIdx.x;
    const int kbase = blockIdx.x * 256;
    const int n0    = blockIdx.y * 64;
    const int tn = t & 15, tk = t >> 4;
    const int nc = tn * 4;
    const int n_out  = t >> 2;
    const int kc_out = (t & 3) * 16;

    #pragma unroll
    for (int s = 0; s < 4; ++s) {
        const int k0 = kbase + s * 64;
        const int g  = k0 >> 6;
        const floatx4 s4 = *reinterpret_cast<const floatx4*>(&S[(size_t)g * Ndim + n0 + nc]);
        const floatx4 z4 = *reinterpret_cast<const floatx4*>(&Z[(size_t)g * Ndim + n0 + nc]);
        intx4 q[4];
        #pragma unroll
        for (int r = 0; r < 4; ++r)
            q[r] = *reinterpret_cast<const intx4*>(&Q[(size_t)(k0 + tk * 4 + r) * Ndim + n0 + nc]);
        if (s) __syncthreads();
        #pragma unroll
        for (int j = 0; j < 4; ++j) {
            const float sv = s4[j], zv = z4[j];
            ushortx4 w;
            w.x = f2bf(fmaf((float)q[0][j], sv, zv));
            w.y = f2bf(fmaf((float)q[1][j], sv, zv));
            w.z = f2bf(fmaf((float)q[2][j], sv, zv));
            w.w = f2bf(fmaf((float)q[3][j], sv, zv));
            *reinterpret_cast<ushortx4*>(&Ls[nc + j][tk * 4]) = w;
        }
        __syncthreads();
        const ushortx8 a = *reinterpret_cast<const ushortx8*>(&Ls[n_out][kc_out]);
        const ushortx8 b = *reinterpret_cast<const ushortx8*>(&Ls[n_out][kc_out + 8]);
        unsigned short* dst = &Wt[(size_t)(n0 + n_out) * Kdim + k0 + kc_out];
        *reinterpret_cast<ushortx8*>(dst)     = a;
        *reinterpret_cast<ushortx8*>(dst + 8) = b;
    }
}

// ---------------- Pre-pass 2: X fp32 -> bf16 ---------------------------------
__global__ void __launch_bounds__(256)
xconv(const float* __restrict__ X, unsigned short* __restrict__ Xw)
{
    const size_t i = ((size_t)blockIdx.x * 256 + threadIdx.x) * 8;
    const floatx4 a = *reinterpret_cast<const floatx4*>(&X[i]);
    const floatx4 b = *reinterpret_cast<const floatx4*>(&X[i + 4]);
    ushortx8 w;
    w[0] = f2bf(a.x); w[1] = f2bf(a.y); w[2] = f2bf(a.z); w[3] = f2bf(a.w);
    w[4] = f2bf(b.x); w[5] = f2bf(b.y); w[6] = f2bf(b.z); w[7] = f2bf(b.w);
    *reinterpret_cast<ushortx8*>(&Xw[i]) = w;
}

// ---------------- Main GEMM: 256x256x64, 8-wave, rotated pre-read pipeline ---
// Both A(u+2) and B(u+2) staged during tile u into buf u&1.
// Tile u phases (buf c = u&1, cn = c^1):
//  phi1: read afB(c);             stage A(u+1)h1->cn, B(u+2)h0->c;  MFMA Q1=afA*bA;  barrier
//  phi2:                          stage B(u+2)h1->c;                MFMA Q2=afB*bA;  vmcnt(4); barrier
//  phi3: read bA'(cn);                                              MFMA Q3=afA*bB;  barrier
//  phi4: read afA'(cn);           stage A(u+2)h0->c;                MFMA Q4=afB*bB;
//        read bB'(cn); lgkmcnt(0); barrier
// Every MFMA's operands were ds_read >=1 phase earlier -> no post-barrier lgkm stall.
// vmcnt(4) drains A(u+1) fully (queue order: A(u+1)h0, A(u+1)h1, B(u+2)h0, B(u+2)h1).
// phi4-end lgkmcnt(0) guarantees this wave's reads of soon-overwritten regions drained
// before the barrier (LDS-DMA vs pending-ds_read cross-wave race guard).

#define STAGE_A(c, kt, h) do { \
    const unsigned short* sp_ = A + aoff + (size_t)((h) * 128) * Kdim + (size_t)(kt) * 64; \
    unsigned short* dp_ = &As[c][((h) * 128 + wave * 16) * 64]; \
    gload_lds16(sp_, dp_); \
    gload_lds16(sp_ + (size_t)8 * Kdim, dp_ + 8 * 64); \
} while (0)

#define STAGE_B(c, kt, h) do { \
    const unsigned short* sp_ = B + boff + (size_t)((h) * 128) * Kdim + (size_t)(kt) * 64; \
    unsigned short* dp_ = &Bs[c][((h) * 128 + wave * 16) * 64]; \
    gload_lds16(sp_, dp_); \
    gload_lds16(sp_ + (size_t)8 * Kdim, dp_ + 8 * 64); \
} while (0)

#define LDA_(c, i, kh) (*reinterpret_cast<const short8*>( \
    &As[c][(wm + (i) * 16 + lrow) * 64 + (((kh) * 4 + quad) ^ lsw) * 8]))
#define LDB_(c, j, kh) (*reinterpret_cast<const short8*>( \
    &Bs[c][(wn + (j) * 16 + lrow) * 64 + (((kh) * 4 + quad) ^ lsw) * 8]))

#define SBAR()  __builtin_amdgcn_sched_barrier(0)

// 16 MFMA: all 8 k-half-0 first (independent), then 8 k-half-1 (dep distance 8)
#define MFMA_Q(AF, BF, IO, JO) do { \
    __builtin_amdgcn_s_setprio(1); \
    _Pragma("unroll") \
    for (int kh_ = 0; kh_ < 2; ++kh_) { \
        _Pragma("unroll") \
        for (int i_ = 0; i_ < 4; ++i_) { \
            _Pragma("unroll") \
            for (int j_ = 0; j_ < 2; ++j_) { \
                acc[(IO) + i_][(JO) + j_] = __builtin_amdgcn_mfma_f32_16x16x32_bf16( \
                    AF[i_][kh_], BF[j_][kh_], acc[(IO) + i_][(JO) + j_], 0, 0, 0); \
            } \
        } \
    } \
    __builtin_amdgcn_s_setprio(0); \
} while (0)

__global__ void __launch_bounds__(512, 2)
gemm_bf16_8p(const unsigned short* __restrict__ A, const unsigned short* __restrict__ B,
             const float* __restrict__ bias, float* __restrict__ O)
{
    __shared__ unsigned short As[2][256 * 64];   // 64 KiB
    __shared__ unsigned short Bs[2][256 * 64];   // 64 KiB

    constexpr int NT = Kdim / 64;                // 64 K-tiles

    // XCD-aware bijective swizzle (768 % 8 == 0), then 8-row-band grouping
    const int nblk = Ndim / 256;                 // 48
    const int cpx  = (Mdim / 256) * nblk / 8;    // 96 blocks per XCD
    const int bid  = blockIdx.x;
    const int swz  = (bid & 7) * cpx + (bid >> 3);
    const int gsz  = 8 * nblk;                   // 384
    const int grp  = swz / gsz;
    const int r    = swz % gsz;
    const int m0   = (grp * 8 + (r & 7)) * 256;
    const int n0   = (r >> 3) * 256;

    const int t    = threadIdx.x;
    const int wave = t >> 6;                     // 0..7
    const int lane = t & 63;
    const int wm   = (wave >> 2) * 128;          // 128-row half
    const int wn   = (wave & 3) * 64;            // 64-col quarter
    const int lrow = lane & 15;
    const int quad = lane >> 4;
    const int lsw  = lrow & 7;

    // staging: lane fills physical chunk (lane&7) of row (lane>>3) in an 8-row slab;
    // that chunk must hold logical k-chunk (lane&7)^(row&7)
    const int srow = lane >> 3;
    const int scol = ((lane & 7) ^ srow) * 8;
    const size_t aoff = (size_t)(m0 + wave * 16 + srow) * Kdim + scol;
    const size_t boff = (size_t)(n0 + wave * 16 + srow) * Kdim + scol;

    floatx4 acc[8][4];
    #pragma unroll
    for (int i = 0; i < 8; ++i)
        #pragma unroll
        for (int j = 0; j < 4; ++j)
            acc[i][j] = floatx4{0.f, 0.f, 0.f, 0.f};

    short8 afA[4][2];   // A-M0 frags of current tile
    short8 afB[4][2];   // A-M1 frags
    short8 bA[2][2];    // B-N01 frags
    short8 bB[2][2];    // B-N23 frags

    // -------- prologue: stage A0,B0 (buf0), B1 (buf1), A1h0 (buf1) ----------
    // queue: A0h0 A0h1 B0h0 B0h1 B1h0 B1h1 A1h0  (14 loads)
    STAGE_A(0, 0, 0); STAGE_A(0, 0, 1);
    STAGE_B(0, 0, 0); STAGE_B(0, 0, 1);
    STAGE_B(1, 1, 0); STAGE_B(1, 1, 1);
    STAGE_A(1, 1, 0);
    asm volatile("s_waitcnt vmcnt(2)" ::: "memory");   // A0,B0,B1 done; A1h0 in flight
    __builtin_amdgcn_s_barrier();
    SBAR();
    #pragma unroll
    for (int i = 0; i < 4; ++i) { afA[i][0] = LDA_(0, i, 0); afA[i][1] = LDA_(0, i, 1); }
    #pragma unroll
    for (int j = 0; j < 2; ++j) { bA[j][0] = LDB_(0, j, 0); bA[j][1] = LDB_(0, j, 1); }
    #pragma unroll
    for (int j = 0; j < 2; ++j) { bB[j][0] = LDB_(0, j + 2, 0); bB[j][1] = LDB_(0, j + 2, 1); }
    asm volatile("s_waitcnt lgkmcnt(0)" ::: "memory");
    SBAR();
    __builtin_amdgcn_s_barrier();
    SBAR();

    for (int u = 0; u < NT; ++u) {
        const int c = u & 1, cn = c ^ 1;

        // ---- phi1: read afB(c); stage A(u+1)h1 then B(u+2)h0; MFMA Q1 ----
        #pragma unroll
        for (int i = 0; i < 4; ++i) { afB[i][0] = LDA_(c, i + 4, 0); afB[i][1] = LDA_(c, i + 4, 1); }
        if (u + 1 < NT) STAGE_A(cn, u + 1, 1);
        if (u + 2 < NT) STAGE_B(c, u + 2, 0);
        MFMA_Q(afA, bA, 0, 0);
        SBAR();
        __builtin_amdgcn_s_barrier();
        SBAR();

        // ---- phi2: stage B(u+2)h1; MFMA Q2; counted vmcnt; barrier ----
        if (u + 2 < NT) STAGE_B(c, u + 2, 1);
        MFMA_Q(afB, bA, 4, 0);
        SBAR();
        if (u < NT - 2) { asm volatile("s_waitcnt vmcnt(4)" ::: "memory"); }
        else            { asm volatile("s_waitcnt vmcnt(0)" ::: "memory"); }
        __builtin_amdgcn_s_barrier();
        SBAR();

        // ---- phi3: pre-read bA'(u+1); MFMA Q3 ----
        if (u + 1 < NT) {
            #pragma unroll
            for (int j = 0; j < 2; ++j) { bA[j][0] = LDB_(cn, j, 0); bA[j][1] = LDB_(cn, j, 1); }
        }
        MFMA_Q(afA, bB, 0, 2);
        SBAR();
        __builtin_amdgcn_s_barrier();
        SBAR();

        // ---- phi4: pre-read afA'(u+1); stage A(u+2)h0; MFMA Q4; read bB'; drain ----
        if (u + 1 < NT) {
            #pragma unroll
            for (int i = 0; i < 4; ++i) { afA[i][0] = LDA_(cn, i, 0); afA[i][1] = LDA_(cn, i, 1); }
        }
        if (u + 2 < NT) STAGE_A(c, u + 2, 0);
        MFMA_Q(afB, bB, 4, 2);
        SBAR();
        if (u + 1 < NT) {
            #pragma unroll
            for (int j = 0; j < 2; ++j) { bB[j][0] = LDB_(cn, j + 2, 0); bB[j][1] = LDB_(cn, j + 2, 1); }
        }
        asm volatile("s_waitcnt lgkmcnt(0)" ::: "memory");
        SBAR();
        __builtin_amdgcn_s_barrier();
        SBAR();
    }

    // -------- epilogue --------
    #pragma unroll
    for (int j = 0; j < 4; ++j) {
        const int col = n0 + wn + j * 16 + lrow;
        const float bv = bias[col];
        #pragma unroll
        for (int i = 0; i < 8; ++i) {
            const int rbase = m0 + wm + i * 16 + quad * 4;
            #pragma unroll
            for (int rr = 0; rr < 4; ++rr)
                O[(size_t)(rbase + rr) * Ndim + col] = acc[i][j][rr] + bv;
        }
    }
}

// ---------------- Fallback (fused, ws-independent) ---------------------------
__global__ void __launch_bounds__(256)
w2a16_gemm_fb(const float* __restrict__ X, const int* __restrict__ Q,
              const float* __restrict__ S, const float* __restrict__ Z,
              const float* __restrict__ bias, float* __restrict__ O)
{
    __shared__ unsigned short Asf[128][72];
    __shared__ unsigned short Bsf[128][72];
    const int t  = threadIdx.x;
    const int n0 = blockIdx.x * 128;
    const int m0 = blockIdx.y * 128;
    const int wave = t >> 6, lane = t & 63;
    const int wm = (wave & 1) * 64, wn = (wave >> 1) * 64;
    const int lrow = lane & 15, quad = lane >> 4;
    floatx4 acc[4][4];
    #pragma unroll
    for (int i = 0; i < 4; ++i)
        #pragma unroll
        for (int j = 0; j < 4; ++j) acc[i][j] = floatx4{0.f, 0.f, 0.f, 0.f};
    const int a_row0 = t >> 4, a_c = (t & 15) * 4;
    const int b_n = t & 127, b_k0 = (t >> 7) * 32;
    for (int k0 = 0; k0 < Kdim; k0 += 64) {
        #pragma unroll
        for (int i = 0; i < 8; ++i) {
            const int row = a_row0 + i * 16;
            const floatx4 v = *reinterpret_cast<const floatx4*>(
                &X[(size_t)(m0 + row) * Kdim + k0 + a_c]);
            ushortx4 w;
            w.x = f2bf(v.x); w.y = f2bf(v.y); w.z = f2bf(v.z); w.w = f2bf(v.w);
            *reinterpret_cast<ushortx4*>(&Asf[row][a_c]) = w;
        }
        const int g = k0 >> 6;
        const float s = S[(size_t)g * Ndim + n0 + b_n];
        const float z = Z[(size_t)g * Ndim + n0 + b_n];
        #pragma unroll
        for (int i = 0; i < 8; ++i) {
            const int kk = b_k0 + i * 4;
            const int* qp = &Q[(size_t)(k0 + kk) * Ndim + n0 + b_n];
            ushortx4 w;
            w.x = f2bf(fmaf((float)qp[0],                s, z));
            w.y = f2bf(fmaf((float)qp[(size_t)Ndim],     s, z));
            w.z = f2bf(fmaf((float)qp[(size_t)2 * Ndim], s, z));
            w.w = f2bf(fmaf((float)qp[(size_t)3 * Ndim], s, z));
            *reinterpret_cast<ushortx4*>(&Bsf[b_n][kk]) = w;
        }
        __syncthreads();
        #pragma unroll
        for (int kk = 0; kk < 64; kk += 32) {
            short8 afv[4], bfv[4];
            #pragma unroll
            for (int i = 0; i < 4; ++i)
                afv[i] = *reinterpret_cast<const short8*>(&Asf[wm + i * 16 + lrow][kk + quad * 8]);
            #pragma unroll
            for (int j = 0; j < 4; ++j)
                bfv[j] = *reinterpret_cast<const short8*>(&Bsf[wn + j * 16 + lrow][kk + quad * 8]);
            #pragma unroll
            for (int i = 0; i < 4; ++i)
                #pragma unroll
                for (int j = 0; j < 4; ++j)
                    acc[i][j] = __builtin_amdgcn_mfma_f32_16x16x32_bf16(afv[i], bfv[j], acc[i][j], 0, 0, 0);
        }
        __syncthreads();
    }
    #pragma unroll
    for (int j = 0; j < 4; ++j) {
        const int col = n0 + wn + j * 16 + lrow;
        const float bv = bias[col];
        #pragma unroll
        for (int i = 0; i < 4; ++i) {
            const int rbase = m0 + wm + i * 16 + quad * 4;
            #pragma unroll
            for (int rr = 0; rr < 4; ++rr)
                O[(size_t)(rbase + rr) * Ndim + col] = acc[i][j][rr] + bv;
        }
    }
}

extern "C" void kernel_launch(void* const* d_in, const int* in_sizes, int n_in,
                              void* d_out, int out_size, void* d_ws, size_t ws_size,
                              hipStream_t stream) {
    const float* X  = (const float*)d_in[0];
    const int*   Q  = (const int*)d_in[1];
    const float* S  = (const float*)d_in[2];
    const float* Z  = (const float*)d_in[3];
    const float* Bi = (const float*)d_in[4];
    float* O = (float*)d_out;

    const size_t wt_bytes = (size_t)Kdim * Ndim * 2;
    const size_t xw_bytes = (size_t)Mdim * Kdim * 2;

    if (ws_size >= wt_bytes + xw_bytes) {
        unsigned short* Wt = (unsigned short*)d_ws;
        unsigned short* Xw = (unsigned short*)((char*)d_ws + wt_bytes);

        dim3 g1(Kdim / 256, Ndim / 64);                   // (16, 192)
        hipLaunchKernelGGL(dequant_transpose, g1, dim3(256), 0, stream, Q, S, Z, Wt);

        const int xblocks = (Mdim * Kdim) / (256 * 8);    // 8192
        hipLaunchKernelGGL(xconv, dim3(xblocks), dim3(256), 0, stream, X, Xw);

        const int nblocks = (Mdim / 256) * (Ndim / 256);  // 768
        hipLaunchKernelGGL(gemm_bf16_8p, dim3(nblocks), dim3(512), 0, stream, Xw, Wt, Bi, O);
    } else {
        dim3 grid(Ndim / 128, Mdim / 128);
        hipLaunchKernelGGL(w2a16_gemm_fb, grid, dim3(256), 0, stream, X, Q, S, Z, Bi, O);
    }
}